// Round 2
// 11995.496 us; speedup vs baseline: 3.2162x; 3.2162x over previous
//
#include <hip/hip_runtime.h>
#include <hip/hip_bf16.h>

#define NS 32768
#define NT 512
#define HD 64

// d_ws layout (floats):
//   0      f-net weights PACKED (8900)
//   8900   g-net weights PACKED (8900)
//   17800  dts[511]
//   18311  sqdts[511]
//   18822  flag (1.0 if bf16 inputs else 0.0)
//
// Packed per-net layout (so each 16-unit wave slab is contiguous -> s_load_dwordx16):
//   0     W1p [4 jg][4 k][16 jj]      (orig W1[k][jg*16+jj])
//   256   b1  [64]                    (identity)
//   320   W2p [4 jg][64 k][16 jj]
//   4416  b2  [64]
//   4480  W3p [4 jg][64 k][16 jj]
//   8576  b3  [64]
//   8640  W4  [64 k][4]               (identity: == [4 jg][16 kk][4])
//   8896  b4  [4]
#define WS_NET 8900
#define WS_DTS 17800
#define WS_SQ 18311
#define WS_FLAG 18822

struct P16 { const void* p[16]; };

__global__ void prep_kernel(P16 wp, const void* timesp, float* ws) {
  unsigned first = ((const unsigned*)timesp)[0];
  bool isbf = (first != 0u);  // times[0]==0.0f -> fp32 dword is 0; bf16 pair is 0x3C240000
  int tid = blockIdx.x * blockDim.x + threadIdx.x;
  int stride = gridDim.x * blockDim.x;
  for (int idx = tid; idx < WS_DTS + (NT - 1); idx += stride) {
    if (idx < WS_DTS) {
      int net = (idx >= WS_NET) ? 1 : 0;
      int r = idx - net * WS_NET;
      int ti, src;
      if (r < 256) {
        int jg = r >> 6, rem = r & 63, k = rem >> 4, jj = rem & 15;
        ti = 0; src = k * 64 + jg * 16 + jj;
      } else if (r < 320) {
        ti = 1; src = r - 256;
      } else if (r < 4416) {
        int rr = r - 320; int jg = rr >> 10, rem = rr & 1023, k = rem >> 4, jj = rem & 15;
        ti = 2; src = k * 64 + jg * 16 + jj;
      } else if (r < 4480) {
        ti = 3; src = r - 4416;
      } else if (r < 8576) {
        int rr = r - 4480; int jg = rr >> 10, rem = rr & 1023, k = rem >> 4, jj = rem & 15;
        ti = 4; src = k * 64 + jg * 16 + jj;
      } else if (r < 8640) {
        ti = 5; src = r - 8576;
      } else if (r < 8896) {
        ti = 6; src = r - 8640;
      } else {
        ti = 7; src = r - 8896;
      }
      ti += net * 8;
      float v = isbf ? __bfloat162float(((const __hip_bfloat16*)wp.p[ti])[src])
                     : ((const float*)wp.p[ti])[src];
      ws[idx] = v;
    } else {
      int t = idx - WS_DTS;
      float t0, t1;
      if (isbf) {
        t0 = __bfloat162float(((const __hip_bfloat16*)timesp)[t]);
        t1 = __bfloat162float(((const __hip_bfloat16*)timesp)[t + 1]);
      } else {
        t0 = ((const float*)timesp)[t];
        t1 = ((const float*)timesp)[t + 1];
      }
      float dt = t1 - t0;
      ws[WS_DTS + t] = dt;
      ws[WS_SQ + t] = sqrtf(dt);
    }
  }
  if (blockIdx.x == 0 && threadIdx.x == 0) ws[WS_FLAG] = isbf ? 1.0f : 0.0f;
}

__device__ __forceinline__ float lipswish(float x) {
  float e = __expf(-x);
  return 0.909f * x * __builtin_amdgcn_rcpf(1.0f + e);
}

__device__ __forceinline__ unsigned short f2bs(float x) {
  return __bfloat16_as_ushort(__float2bfloat16(x));
}

__device__ __forceinline__ void store_out(void* outp, bool isbf, int sample, int t,
                                          const float v[4]) {
  if (isbf) {
    uint2 u;
    u.x = (unsigned)f2bs(v[0]) | ((unsigned)f2bs(v[1]) << 16);
    u.y = (unsigned)f2bs(v[2]) | ((unsigned)f2bs(v[3]) << 16);
    ((uint2*)outp)[(size_t)sample * NT + t] = u;
  } else {
    float4 f = make_float4(v[0], v[1], v[2], v[3]);
    ((float4*)outp)[(size_t)sample * NT + t] = f;
  }
}

// block = 512 threads = 8 waves per 64-sample tile.
// wave = (net, jgroup): waves 0-3 compute f-net units [16*jg,16*jg+16),
// waves 4-7 the same for g-net. Hidden vectors exchanged through LDS
// h[buf][net][unit][sample] (stride-1 across lanes -> conflict-free).
// NOTE: the net dimension is essential — f and g waves each need their own
// 64-unit hidden state (round-1 bug: both nets clobbered one buffer).
// L4 is k-split: each wave reduces its own in-register h3 slice; partials
// summed through exch[]. Every wave redundantly updates its copy of y.
// Weight slabs are contiguous per wave (packed by prep) and the base is
// readfirstlane-forced uniform -> s_load_dwordx16 operands, zero VGPR cost.
// LDS: h 64KB + exch 16KB = 80KB -> 2 blocks/CU = 16 waves/CU = 4 waves/SIMD.
__global__ __launch_bounds__(512, 4) void sde_kernel(
    const void* __restrict__ y0p, const void* __restrict__ noisep,
    const float* __restrict__ ws, void* __restrict__ outp) {
  const int tid = threadIdx.x;
  const int lane = tid & 63;
  const int uwv = __builtin_amdgcn_readfirstlane(tid >> 6);  // 0..7 wave-uniform
  const int unet = uwv >> 2;  // 0 = f-net, 1 = g-net
  const int ujg = uwv & 3;    // which 16-unit group
  const int j0 = ujg * 16;
  const int sample = blockIdx.x * 64 + lane;
  const bool isbf = (ws[WS_FLAG] != 0.0f);

  const float* Wb = ws + unet * WS_NET;
  const float* W1p = Wb + ujg * 64;          // [4][16]
  const float* b1p = Wb + 256 + ujg * 16;    // [16]
  const float* W2p = Wb + 320 + ujg * 1024;  // [64][16]
  const float* b2p = Wb + 4416 + ujg * 16;
  const float* W3p = Wb + 4480 + ujg * 1024;
  const float* b3p = Wb + 8576 + ujg * 16;
  const float* W4p = Wb + 8640 + ujg * 64;   // [16][4]
  const float* b4 = Wb + 8896;
  const float* dts = ws + WS_DTS;
  const float* sqdts = ws + WS_SQ;

  __shared__ float h[2][2][HD][64];    // [buf][net][unit][sample] = 64KB
  __shared__ float exch[2][8][4][64];  // [slot][wave][d][sample]   = 16KB

  float y[4];
  if (isbf) {
    const __hip_bfloat16* y0 = (const __hip_bfloat16*)y0p;
#pragma unroll
    for (int d = 0; d < 4; ++d) y[d] = __bfloat162float(y0[sample * 4 + d]);
  } else {
    const float* y0 = (const float*)y0p;
#pragma unroll
    for (int d = 0; d < 4; ++d) y[d] = y0[sample * 4 + d];
  }

  if (uwv == 0) store_out(outp, isbf, sample, 0, y);

  for (int t = 0; t < NT - 1; ++t) {
    // prefetch this step's noise early; used only at the end of the step
    float dw[4];
    if (isbf) {
      uint2 nz = ((const uint2*)noisep)[(size_t)t * NS + sample];
      dw[0] = __uint_as_float((nz.x & 0xffffu) << 16);
      dw[1] = __uint_as_float(nz.x & 0xffff0000u);
      dw[2] = __uint_as_float((nz.y & 0xffffu) << 16);
      dw[3] = __uint_as_float(nz.y & 0xffff0000u);
    } else {
      float4 nz = ((const float4*)noisep)[(size_t)t * NS + sample];
      dw[0] = nz.x; dw[1] = nz.y; dw[2] = nz.z; dw[3] = nz.w;
    }

    float a[16];
    // L1: [4] -> 16 units of this wave
#pragma unroll
    for (int jj = 0; jj < 16; ++jj)
      a[jj] = b1p[jj] + y[0] * W1p[jj] + y[1] * W1p[16 + jj] + y[2] * W1p[32 + jj] +
              y[3] * W1p[48 + jj];
#pragma unroll
    for (int jj = 0; jj < 16; ++jj) h[0][unet][j0 + jj][lane] = lipswish(a[jj]);
    __syncthreads();

    // L2: all 64 of this net -> 16 units of this wave
#pragma unroll
    for (int jj = 0; jj < 16; ++jj) a[jj] = b2p[jj];
#pragma unroll 4
    for (int k = 0; k < HD; ++k) {
      float hk = h[0][unet][k][lane];
      const float* wr = W2p + k * 16;
#pragma unroll
      for (int jj = 0; jj < 16; ++jj) a[jj] = fmaf(hk, wr[jj], a[jj]);
    }
#pragma unroll
    for (int jj = 0; jj < 16; ++jj) h[1][unet][j0 + jj][lane] = lipswish(a[jj]);
    __syncthreads();

    // L3: all 64 of this net -> 16 units, keep h3 in registers
#pragma unroll
    for (int jj = 0; jj < 16; ++jj) a[jj] = b3p[jj];
#pragma unroll 4
    for (int k = 0; k < HD; ++k) {
      float hk = h[1][unet][k][lane];
      const float* wr = W3p + k * 16;
#pragma unroll
      for (int jj = 0; jj < 16; ++jj) a[jj] = fmaf(hk, wr[jj], a[jj]);
    }

    // L4 partial: this wave's 16 h3 values -> partial o[4] (k-split)
    float o[4];
#pragma unroll
    for (int d = 0; d < 4; ++d) o[d] = (ujg == 0) ? b4[d] : 0.0f;
#pragma unroll
    for (int kk = 0; kk < 16; ++kk) {
      float hk = lipswish(a[kk]);
      const float* wr = W4p + kk * 4;
#pragma unroll
      for (int d = 0; d < 4; ++d) o[d] = fmaf(hk, wr[d], o[d]);
    }

    const int slot = t & 1;  // double-buffered exchange
#pragma unroll
    for (int d = 0; d < 4; ++d) exch[slot][uwv][d][lane] = o[d];
    __syncthreads();

    // reduce partials + Euler-Maruyama update (redundant in every wave)
    const float dt = dts[t];
    const float sq = sqdts[t];
#pragma unroll
    for (int d = 0; d < 4; ++d) {
      float fsum = (exch[slot][0][d][lane] + exch[slot][1][d][lane]) +
                   (exch[slot][2][d][lane] + exch[slot][3][d][lane]);
      float gsum = (exch[slot][4][d][lane] + exch[slot][5][d][lane]) +
                   (exch[slot][6][d][lane] + exch[slot][7][d][lane]);
      float drift = fminf(fmaxf(fsum, -100.0f), 100.0f);
      float sp = fmaxf(gsum, 0.0f) + log1pf(__expf(-fabsf(gsum)));  // stable softplus
      float diff = fmaxf(sp, 1e-4f);
      y[d] = y[d] + drift * dt + diff * sq * dw[d];
    }

    if (uwv == 0) store_out(outp, isbf, sample, t + 1, y);
  }
}

extern "C" void kernel_launch(void* const* d_in, const int* in_sizes, int n_in,
                              void* d_out, int out_size, void* d_ws, size_t ws_size,
                              hipStream_t stream) {
  P16 wp;
  for (int i = 0; i < 16; ++i) wp.p[i] = d_in[3 + i];
  float* ws = (float*)d_ws;
  hipLaunchKernelGGL(prep_kernel, dim3(80), dim3(256), 0, stream, wp, d_in[1], ws);
  hipLaunchKernelGGL(sde_kernel, dim3(NS / 64), dim3(512), 0, stream, d_in[0], d_in[2],
                     ws, d_out);
}